// Round 8
// baseline (299.859 us; speedup 1.0000x reference)
//
#include <hip/hip_runtime.h>
#include <hip/hip_bf16.h>
#include <string.h>

typedef __attribute__((ext_vector_type(8))) short short8;
typedef __attribute__((ext_vector_type(4))) float floatx4;

// B=32, T=2048, D=512, U=512, M = B*T = 65536

__device__ inline uint packbf2(float lo, float hi) {
    __hip_bfloat162 h = __float22bfloat162_rn(make_float2(lo, hi));
    uint r; memcpy(&r, &h, 4); return r;
}

__device__ inline float tanh_fast(float x) {
    x = fminf(15.f, fmaxf(-15.f, x));
    float e = __expf(2.f * x);
    return __fdividef(e - 1.f, e + 1.f);
}

// async global->LDS 16B: lds dest = wave-uniform base (+ lane*16 implicit),
// global src = per-lane address. bf16/ushort flavor (proven in round 6).
__device__ inline void gload_lds16u(const ushort* g, ushort* l) {
    __builtin_amdgcn_global_load_lds(
        (const __attribute__((address_space(1))) unsigned int*)g,
        (__attribute__((address_space(3))) unsigned int*)l,
        16, 0, 0);
}

// ---- kernel 0: fused prep.
// blocks 0..127:   pack W1_enc -> bf16 MFMA B-frag chunks (Wp)
// blocks 128..383: dec[b][u] = h_dec[b]·W1_dec[:,u] + b1[u]
// blocks 384..447: zero ctx (for kctx2 atomicAdd)
__global__ void kprep(const float* __restrict__ W1, const float* __restrict__ hdec,
                      const float* __restrict__ b1, ushort* __restrict__ Wp,
                      float* __restrict__ dec, float* __restrict__ ctx) {
    __shared__ float red[4][64];
    int tid = threadIdx.x;
    if (blockIdx.x < 128) {
        int wid = blockIdx.x * 4 + (tid >> 6);       // 0..511 chunks
        int l = tid & 63;
        int kc = wid >> 5, ng = wid & 31;
        int m = l & 15, g = l >> 4;
        const float* src = W1 + (size_t)(kc * 32 + g * 8) * 512 + ng * 16 + m;
        uint u4[4];
        #pragma unroll
        for (int e = 0; e < 4; ++e)
            u4[e] = packbf2(src[(size_t)(2 * e) * 512], src[(size_t)(2 * e + 1) * 512]);
        *(uint4*)(Wp + (size_t)wid * 512 + l * 8) = *(uint4*)u4;
    } else if (blockIdx.x < 384) {
        int bid = blockIdx.x - 128;                  // 0..255
        int b = bid >> 3, ug = bid & 7;
        int u = ug * 64 + (tid & 63), dq = tid >> 6;
        const float* hb = hdec + b * 512 + dq * 128;
        const float* w = W1 + (size_t)(512 + dq * 128) * 512 + u;
        float a = 0.f;
        #pragma unroll 8
        for (int d = 0; d < 128; ++d)
            a += hb[d] * w[(size_t)d * 512];
        red[dq][tid & 63] = a;
        __syncthreads();
        if (tid < 64)
            dec[b * 512 + ug * 64 + tid] =
                red[0][tid] + red[1][tid] + red[2][tid] + red[3][tid] + b1[ug * 64 + tid];
    } else {
        ctx[(blockIdx.x - 384) * 256 + tid] = 0.f;   // 64 blocks x 256 = 16384
    }
}

// ---- kernel 1: fused GEMM + tanh + dot(W2) -> e2
// Round-2 structure (64-row x 512-col block, 8 waves, wave tile 64x64,
// A VGPR-staged once to LDS in frag order: cvt amortized 8x, 0-conflict)
// + NEW: B (Wp, pre-packed bf16) staged per-kc into a 2x32KB LDS double
// buffer via global_load_lds, one kc ahead of compute. Inner loop is pure
// LDS: 8 ds_read_b128 + 16 MFMA per wave per kc.
// LDS = 64K(A) + 64K(B dbuf) + 2K(red) = 130KB -> 1 block/CU (8 waves).
// launch_bounds(512,2): 256-reg cap -> no spill possible.
__global__ __launch_bounds__(512, 2) void kgemm(
        const float* __restrict__ A, const ushort* __restrict__ Wp,
        const float* __restrict__ dec, const float* __restrict__ W2,
        float* __restrict__ e2) {
    __shared__ __align__(16) ushort As[32768];       // 64 KB: 64 rows x 512 k bf16
    __shared__ __align__(16) ushort Bs[2][16384];    // 2 x 32 KB: one kc-slab each
    __shared__ float red[8][64];
    const int tid = threadIdx.x;
    const int rowbase = blockIdx.x * 64;
    const int bIdx = blockIdx.x >> 5;                // 32 blocks per batch
    const int lane = tid & 63, wave = tid >> 6;
    const int m = lane & 15, g = lane >> 4;

    // stage B kc-slab (32KB contiguous at Wp + kc*16384) into Bs[buf]:
    // 32 x 1KB wave-issues, linear dest == source layout.
    auto stageB = [&](int buf, int kc) {
        #pragma unroll
        for (int q = 0; q < 4; ++q) {
            int u = wave * 4 + q;                    // 0..31
            gload_lds16u(Wp + (size_t)kc * 16384 + u * 512 + lane * 8,
                         &Bs[buf][u * 512]);
        }
    };

    stageB(0, 0);                                    // B kc=0 in flight under A-stage

    // stage A tile: 64 rows x 512 k, fp32 -> bf16, fragment-chunk order
    #pragma unroll
    for (int p = 0; p < 8; ++p) {
        int s = tid + 512 * p;                       // 0..4095 lane-slots
        int chunk = s >> 6, l = s & 63;
        int i = chunk >> 4, kcc = chunk & 15;
        int mm = l & 15, gg = l >> 4;
        const float* gp = A + (size_t)(rowbase + i * 16 + mm) * 512 + kcc * 32 + gg * 8;
        float4 f0 = *(const float4*)gp;
        float4 f1 = *(const float4*)(gp + 4);
        uint4 u;
        u.x = packbf2(f0.x, f0.y); u.y = packbf2(f0.z, f0.w);
        u.z = packbf2(f1.x, f1.y); u.w = packbf2(f1.z, f1.w);
        *(uint4*)&As[chunk * 512 + l * 8] = u;
    }
    __syncthreads();                                 // A in LDS; B kc=0 drained (vmcnt 0)

    floatx4 acc[4][4];
    #pragma unroll
    for (int i = 0; i < 4; i++)
        #pragma unroll
        for (int j = 0; j < 4; j++) acc[i][j] = (floatx4){0.f, 0.f, 0.f, 0.f};

    const int ng0 = wave * 4;                        // wave covers cols wave*64..+63

    for (int kc = 0; kc < 16; ++kc) {
        if (kc < 15) stageB((kc + 1) & 1, kc + 1);   // DMA next slab under compute
        const ushort* bsl = Bs[kc & 1];
        short8 bfr[4];
        #pragma unroll
        for (int j = 0; j < 4; ++j)
            bfr[j] = *(const short8*)&bsl[(ng0 + j) * 512 + lane * 8];
        short8 afr[4];
        #pragma unroll
        for (int i = 0; i < 4; ++i)
            afr[i] = *(const short8*)&As[(i * 16 + kc) * 512 + lane * 8];
        #pragma unroll
        for (int j = 0; j < 4; ++j)
            #pragma unroll
            for (int i = 0; i < 4; ++i)
                acc[i][j] = __builtin_amdgcn_mfma_f32_16x16x32_bf16(afr[i], bfr[j], acc[i][j], 0, 0, 0);
        __syncthreads();                             // drains next-slab DMA (covered)
    }

    // epilogue: z += dec; p = sum_u tanh(z)*W2[u]; reduce 16 lanes + 8 waves
    float w2v[4], dv[4];
    #pragma unroll
    for (int j = 0; j < 4; j++) {
        int n = wave * 64 + j * 16 + m;
        w2v[j] = W2[n];
        dv[j]  = dec[bIdx * 512 + n];
    }
    #pragma unroll
    for (int i = 0; i < 4; i++) {
        #pragma unroll
        for (int r = 0; r < 4; r++) {
            float p = 0.f;
            #pragma unroll
            for (int j = 0; j < 4; j++)
                p += tanh_fast(acc[i][j][r] + dv[j]) * w2v[j];
            p += __shfl_xor(p, 1, 16);
            p += __shfl_xor(p, 2, 16);
            p += __shfl_xor(p, 4, 16);
            p += __shfl_xor(p, 8, 16);
            if (m == 0) red[wave][i * 16 + g * 4 + r] = p;
        }
    }
    __syncthreads();
    if (tid < 64) {
        float s = 0.f;
        #pragma unroll
        for (int w = 0; w < 8; ++w) s += red[w][tid];
        e2[rowbase + tid] = s;
    }
}

// ---- kernel 2: fused softmax + partial context -> atomicAdd into ctx.
// Block (b,ch): recompute row softmax stats from e2 (fixed reduction order =>
// identical across blocks of same b), write own 64-wide attn slice,
// then ctx[b][:] += sum_{t in chunk} attn*h_enc (atomic, fp32).
__global__ __launch_bounds__(512) void kctx2(const float* __restrict__ A,
        const float* __restrict__ e2, const float* __restrict__ b2,
        float* __restrict__ attn, float* __restrict__ ctx) {
    __shared__ float at[64];
    __shared__ float4 red[3][128];
    __shared__ float smax[8], ssum[8];
    int b = blockIdx.x, ch = blockIdx.y, tid = threadIdx.x;
    int lane = tid & 63, wave = tid >> 6;
    float b2v = b2[0];
    const float* erow = e2 + b * 2048;

    float f[4];
    float mx = 0.f;                                   // relu values >= 0
    #pragma unroll
    for (int i = 0; i < 4; i++) {
        f[i] = fmaxf(erow[i * 512 + tid] + b2v, 0.f);
        mx = fmaxf(mx, f[i]);
    }
    #pragma unroll
    for (int off = 1; off < 64; off <<= 1) mx = fmaxf(mx, __shfl_xor(mx, off));
    if (lane == 0) smax[wave] = mx;
    __syncthreads();
    #pragma unroll
    for (int w = 0; w < 8; ++w) mx = fmaxf(mx, smax[w]);
    float s = 0.f;
    #pragma unroll
    for (int i = 0; i < 4; i++) s += __expf(f[i] - mx);
    #pragma unroll
    for (int off = 1; off < 64; off <<= 1) s += __shfl_xor(s, off);
    if (lane == 0) ssum[wave] = s;
    __syncthreads();
    s = 0.f;
    #pragma unroll
    for (int w = 0; w < 8; ++w) s += ssum[w];
    float inv = 1.f / s;

    if (tid < 64) {
        float z = fmaxf(erow[ch * 64 + tid] + b2v, 0.f);
        float a = __expf(z - mx) * inv;
        at[tid] = a;
        attn[b * 2048 + ch * 64 + tid] = a;
    }
    __syncthreads();

    int dt = tid & 127, th = tid >> 7;               // th in 0..3, 16 t each
    const float* base = A + ((size_t)b * 2048 + ch * 64 + th * 16) * 512 + dt * 4;
    const float* aw = at + th * 16;
    float4 acc = (float4){0.f, 0.f, 0.f, 0.f};
    #pragma unroll
    for (int tt = 0; tt < 16; ++tt) {
        float a = aw[tt];
        float4 h = *(const float4*)(base + (size_t)tt * 512);
        acc.x += a * h.x; acc.y += a * h.y; acc.z += a * h.z; acc.w += a * h.w;
    }
    if (th) red[th - 1][dt] = acc;
    __syncthreads();
    if (th == 0) {
        float4 o0 = red[0][dt], o1 = red[1][dt], o2 = red[2][dt];
        float* cp = ctx + (size_t)b * 512 + dt * 4;
        atomicAdd(cp + 0, acc.x + o0.x + o1.x + o2.x);
        atomicAdd(cp + 1, acc.y + o0.y + o1.y + o2.y);
        atomicAdd(cp + 2, acc.z + o0.z + o1.z + o2.z);
        atomicAdd(cp + 3, acc.w + o0.w + o1.w + o2.w);
    }
}

extern "C" void kernel_launch(void* const* d_in, const int* in_sizes, int n_in,
                              void* d_out, int out_size, void* d_ws, size_t ws_size,
                              hipStream_t stream) {
    const float* h_enc = (const float*)d_in[0];
    const float* h_dec = (const float*)d_in[1];
    const float* W1    = (const float*)d_in[2];
    const float* b1    = (const float*)d_in[3];
    const float* W2    = (const float*)d_in[4];
    const float* b2    = (const float*)d_in[5];
    float* out  = (float*)d_out;
    float* ctx  = out;              // 32*512
    float* attn = out + 32 * 512;   // 32*2048

    char* ws = (char*)d_ws;
    ushort* Wp = (ushort*)ws;                          // 512 KB @ 0
    float* dec  = (float*)(ws + (512 << 10));          // 64 KB  @ 512K
    float* e2   = (float*)(ws + (576 << 10));          // 256 KB @ 576K

    kprep<<<448, 256, 0, stream>>>(W1, h_dec, b1, Wp, dec, ctx);
    kgemm<<<1024, 512, 0, stream>>>(h_enc, Wp, dec, W2, e2);
    dim3 g3(32, 32);
    kctx2<<<g3, 512, 0, stream>>>(h_enc, e2, b2, attn, ctx);
}

// Round 10
// 281.863 us; speedup vs baseline: 1.0638x; 1.0638x over previous
//
#include <hip/hip_runtime.h>
#include <hip/hip_bf16.h>
#include <string.h>

typedef __attribute__((ext_vector_type(8))) short short8;
typedef __attribute__((ext_vector_type(4))) float floatx4;

// B=32, T=2048, D=512, U=512, M = B*T = 65536

__device__ inline uint packbf2(float lo, float hi) {
    __hip_bfloat162 h = __float22bfloat162_rn(make_float2(lo, hi));
    uint r; memcpy(&r, &h, 4); return r;
}

__device__ inline float tanh_fast(float x) {
    x = fminf(15.f, fmaxf(-15.f, x));
    float e = __expf(2.f * x);
    return __fdividef(e - 1.f, e + 1.f);
}

// ---- kernel 0: fused prep (proven, rounds 7-8).
// blocks 0..127:   pack W1_enc -> bf16 MFMA B-frag chunks (Wp)
// blocks 128..383: dec[b][u] = h_dec[b]·W1_dec[:,u] + b1[u]
// blocks 384..447: zero ctx (for kctx2 atomicAdd)
__global__ void kprep(const float* __restrict__ W1, const float* __restrict__ hdec,
                      const float* __restrict__ b1, ushort* __restrict__ Wp,
                      float* __restrict__ dec, float* __restrict__ ctx) {
    __shared__ float red[4][64];
    int tid = threadIdx.x;
    if (blockIdx.x < 128) {
        int wid = blockIdx.x * 4 + (tid >> 6);       // 0..511 chunks
        int l = tid & 63;
        int kc = wid >> 5, ng = wid & 31;
        int m = l & 15, g = l >> 4;
        const float* src = W1 + (size_t)(kc * 32 + g * 8) * 512 + ng * 16 + m;
        uint u4[4];
        #pragma unroll
        for (int e = 0; e < 4; ++e)
            u4[e] = packbf2(src[(size_t)(2 * e) * 512], src[(size_t)(2 * e + 1) * 512]);
        *(uint4*)(Wp + (size_t)wid * 512 + l * 8) = *(uint4*)u4;
    } else if (blockIdx.x < 384) {
        int bid = blockIdx.x - 128;                  // 0..255
        int b = bid >> 3, ug = bid & 7;
        int u = ug * 64 + (tid & 63), dq = tid >> 6;
        const float* hb = hdec + b * 512 + dq * 128;
        const float* w = W1 + (size_t)(512 + dq * 128) * 512 + u;
        float a = 0.f;
        #pragma unroll 8
        for (int d = 0; d < 128; ++d)
            a += hb[d] * w[(size_t)d * 512];
        red[dq][tid & 63] = a;
        __syncthreads();
        if (tid < 64)
            dec[b * 512 + ug * 64 + tid] =
                red[0][tid] + red[1][tid] + red[2][tid] + red[3][tid] + b1[ug * 64 + tid];
    } else {
        ctx[(blockIdx.x - 384) * 256 + tid] = 0.f;   // 64 blocks x 256 = 16384
    }
}

// ---- kernel 1: fused GEMM + tanh + dot(W2) -> e2
// Round-0/2 proven structure, halved tile: BM=32 rows x 512 cols, 8 waves,
// wave tile 32x64 (acc[2][4] = 32 VGPR). LDS = 32KB A-tile + 1KB red ->
// 4 blocks/CU = 32 waves/CU (2x the wave pool of the BM=64 variant) for
// latency hiding. Barrier-free K-loop, zero staging conflicts, no spill
// (~100 regs < 128 cap at launch_bounds(512,4)).
__global__ __launch_bounds__(512, 4) void kgemm(
        const float* __restrict__ A, const ushort* __restrict__ Wp,
        const float* __restrict__ dec, const float* __restrict__ W2,
        float* __restrict__ e2) {
    __shared__ __align__(16) ushort As[16384];   // 32 KB: 32 rows x 512 k bf16
    __shared__ float red[8][32];                 // 1 KB
    const int tid = threadIdx.x;
    const int rowbase = blockIdx.x * 32;
    const int bIdx = blockIdx.x >> 6;            // 64 blocks per batch

    // stage A tile: 32 rows x 512 k, fp32 -> bf16, fragment-chunk order
    #pragma unroll
    for (int p = 0; p < 4; ++p) {
        int s = tid + 512 * p;                   // 0..2047 lane-slots
        int chunk = s >> 6, l = s & 63;          // chunk 0..31 = i*16 + kcc
        int i = chunk >> 4, kcc = chunk & 15;
        int mm = l & 15, gg = l >> 4;
        const float* gp = A + (size_t)(rowbase + i * 16 + mm) * 512 + kcc * 32 + gg * 8;
        float4 f0 = *(const float4*)gp;
        float4 f1 = *(const float4*)(gp + 4);
        uint4 u;
        u.x = packbf2(f0.x, f0.y); u.y = packbf2(f0.z, f0.w);
        u.z = packbf2(f1.x, f1.y); u.w = packbf2(f1.z, f1.w);
        *(uint4*)&As[chunk * 512 + l * 8] = u;
    }
    __syncthreads();

    const int lane = tid & 63, wave = tid >> 6;
    const int c = lane & 15, g = lane >> 4;

    floatx4 acc[2][4];
    #pragma unroll
    for (int i = 0; i < 2; i++)
        #pragma unroll
        for (int j = 0; j < 4; j++) acc[i][j] = (floatx4){0.f, 0.f, 0.f, 0.f};

    const int ng0 = wave * 4;                    // wave covers cols wave*64..+63
    #pragma unroll 2
    for (int kc = 0; kc < 16; ++kc) {
        short8 bfr[4];
        #pragma unroll
        for (int j = 0; j < 4; ++j)
            bfr[j] = *(const short8*)&Wp[(size_t)(kc * 32 + ng0 + j) * 512 + lane * 8];
        short8 afr[2];
        #pragma unroll
        for (int i = 0; i < 2; ++i)
            afr[i] = *(const short8*)&As[(i * 16 + kc) * 512 + lane * 8];
        #pragma unroll
        for (int j = 0; j < 4; ++j)
            #pragma unroll
            for (int i = 0; i < 2; ++i)
                acc[i][j] = __builtin_amdgcn_mfma_f32_16x16x32_bf16(afr[i], bfr[j], acc[i][j], 0, 0, 0);
    }

    // epilogue: z += dec; p = sum_u tanh(z)*W2[u]; reduce 16 lanes + 8 waves
    float w2v[4], dv[4];
    #pragma unroll
    for (int j = 0; j < 4; j++) {
        int n = wave * 64 + j * 16 + c;
        w2v[j] = W2[n];
        dv[j]  = dec[bIdx * 512 + n];
    }
    #pragma unroll
    for (int i = 0; i < 2; i++) {
        #pragma unroll
        for (int r = 0; r < 4; r++) {
            float p = 0.f;
            #pragma unroll
            for (int j = 0; j < 4; j++)
                p += tanh_fast(acc[i][j][r] + dv[j]) * w2v[j];
            p += __shfl_xor(p, 1, 16);
            p += __shfl_xor(p, 2, 16);
            p += __shfl_xor(p, 4, 16);
            p += __shfl_xor(p, 8, 16);
            if (c == 0) red[wave][i * 16 + g * 4 + r] = p;
        }
    }
    __syncthreads();
    if (tid < 32) {
        float s = 0.f;
        #pragma unroll
        for (int w = 0; w < 8; ++w) s += red[w][tid];
        e2[rowbase + tid] = s;
    }
}

// ---- kernel 2: fused softmax + partial context -> atomicAdd into ctx (proven).
__global__ __launch_bounds__(512) void kctx2(const float* __restrict__ A,
        const float* __restrict__ e2, const float* __restrict__ b2,
        float* __restrict__ attn, float* __restrict__ ctx) {
    __shared__ float at[64];
    __shared__ float4 red[3][128];
    __shared__ float smax[8], ssum[8];
    int b = blockIdx.x, ch = blockIdx.y, tid = threadIdx.x;
    int lane = tid & 63, wave = tid >> 6;
    float b2v = b2[0];
    const float* erow = e2 + b * 2048;

    float f[4];
    float mx = 0.f;                                   // relu values >= 0
    #pragma unroll
    for (int i = 0; i < 4; i++) {
        f[i] = fmaxf(erow[i * 512 + tid] + b2v, 0.f);
        mx = fmaxf(mx, f[i]);
    }
    #pragma unroll
    for (int off = 1; off < 64; off <<= 1) mx = fmaxf(mx, __shfl_xor(mx, off));
    if (lane == 0) smax[wave] = mx;
    __syncthreads();
    #pragma unroll
    for (int w = 0; w < 8; ++w) mx = fmaxf(mx, smax[w]);
    float s = 0.f;
    #pragma unroll
    for (int i = 0; i < 4; i++) s += __expf(f[i] - mx);
    #pragma unroll
    for (int off = 1; off < 64; off <<= 1) s += __shfl_xor(s, off);
    if (lane == 0) ssum[wave] = s;
    __syncthreads();
    s = 0.f;
    #pragma unroll
    for (int w = 0; w < 8; ++w) s += ssum[w];
    float inv = 1.f / s;

    if (tid < 64) {
        float z = fmaxf(erow[ch * 64 + tid] + b2v, 0.f);
        float a = __expf(z - mx) * inv;
        at[tid] = a;
        attn[b * 2048 + ch * 64 + tid] = a;
    }
    __syncthreads();

    int dt = tid & 127, th = tid >> 7;               // th in 0..3, 16 t each
    const float* base = A + ((size_t)b * 2048 + ch * 64 + th * 16) * 512 + dt * 4;
    const float* aw = at + th * 16;
    float4 acc = (float4){0.f, 0.f, 0.f, 0.f};
    #pragma unroll
    for (int tt = 0; tt < 16; ++tt) {
        float a = aw[tt];
        float4 h = *(const float4*)(base + (size_t)tt * 512);
        acc.x += a * h.x; acc.y += a * h.y; acc.z += a * h.z; acc.w += a * h.w;
    }
    if (th) red[th - 1][dt] = acc;
    __syncthreads();
    if (th == 0) {
        float4 o0 = red[0][dt], o1 = red[1][dt], o2 = red[2][dt];
        float* cp = ctx + (size_t)b * 512 + dt * 4;
        atomicAdd(cp + 0, acc.x + o0.x + o1.x + o2.x);
        atomicAdd(cp + 1, acc.y + o0.y + o1.y + o2.y);
        atomicAdd(cp + 2, acc.z + o0.z + o1.z + o2.z);
        atomicAdd(cp + 3, acc.w + o0.w + o1.w + o2.w);
    }
}

extern "C" void kernel_launch(void* const* d_in, const int* in_sizes, int n_in,
                              void* d_out, int out_size, void* d_ws, size_t ws_size,
                              hipStream_t stream) {
    const float* h_enc = (const float*)d_in[0];
    const float* h_dec = (const float*)d_in[1];
    const float* W1    = (const float*)d_in[2];
    const float* b1    = (const float*)d_in[3];
    const float* W2    = (const float*)d_in[4];
    const float* b2    = (const float*)d_in[5];
    float* out  = (float*)d_out;
    float* ctx  = out;              // 32*512
    float* attn = out + 32 * 512;   // 32*2048

    char* ws = (char*)d_ws;
    ushort* Wp = (ushort*)ws;                          // 512 KB @ 0
    float* dec  = (float*)(ws + (512 << 10));          // 64 KB  @ 512K
    float* e2   = (float*)(ws + (576 << 10));          // 256 KB @ 576K

    kprep<<<448, 256, 0, stream>>>(W1, h_dec, b1, Wp, dec, ctx);
    kgemm<<<2048, 512, 0, stream>>>(h_enc, Wp, dec, W2, e2);
    dim3 g3(32, 32);
    kctx2<<<g3, 512, 0, stream>>>(h_enc, e2, b2, attn, ctx);
}

// Round 11
// 272.021 us; speedup vs baseline: 1.1023x; 1.0362x over previous
//
#include <hip/hip_runtime.h>
#include <hip/hip_bf16.h>
#include <string.h>

typedef __attribute__((ext_vector_type(8))) short short8;
typedef __attribute__((ext_vector_type(4))) float floatx4;

// B=32, T=2048, D=512, U=512, M = B*T = 65536

__device__ inline uint packbf2(float lo, float hi) {
    __hip_bfloat162 h = __float22bfloat162_rn(make_float2(lo, hi));
    uint r; memcpy(&r, &h, 4); return r;
}

__device__ inline float tanh_fast(float x) {
    x = fminf(15.f, fmaxf(-15.f, x));
    float e = __expf(2.f * x);
    return __fdividef(e - 1.f, e + 1.f);
}

// ---- kernel 0: fused prep (proven, rounds 5/7/8/10).
// blocks 0..127:   pack W1_enc -> bf16 MFMA B-frag chunks (Wp)
// blocks 128..383: dec[b][u] = h_dec[b]·W1_dec[:,u] + b1[u]
// blocks 384..447: zero ctx (for kctx2 atomicAdd)
__global__ void kprep(const float* __restrict__ W1, const float* __restrict__ hdec,
                      const float* __restrict__ b1, ushort* __restrict__ Wp,
                      float* __restrict__ dec, float* __restrict__ ctx) {
    __shared__ float red[4][64];
    int tid = threadIdx.x;
    if (blockIdx.x < 128) {
        int wid = blockIdx.x * 4 + (tid >> 6);       // 0..511 chunks
        int l = tid & 63;
        int kc = wid >> 5, ng = wid & 31;
        int m = l & 15, g = l >> 4;
        const float* src = W1 + (size_t)(kc * 32 + g * 8) * 512 + ng * 16 + m;
        uint u4[4];
        #pragma unroll
        for (int e = 0; e < 4; ++e)
            u4[e] = packbf2(src[(size_t)(2 * e) * 512], src[(size_t)(2 * e + 1) * 512]);
        *(uint4*)(Wp + (size_t)wid * 512 + l * 8) = *(uint4*)u4;
    } else if (blockIdx.x < 384) {
        int bid = blockIdx.x - 128;                  // 0..255
        int b = bid >> 3, ug = bid & 7;
        int u = ug * 64 + (tid & 63), dq = tid >> 6;
        const float* hb = hdec + b * 512 + dq * 128;
        const float* w = W1 + (size_t)(512 + dq * 128) * 512 + u;
        float a = 0.f;
        #pragma unroll 8
        for (int d = 0; d < 128; ++d)
            a += hb[d] * w[(size_t)d * 512];
        red[dq][tid & 63] = a;
        __syncthreads();
        if (tid < 64)
            dec[b * 512 + ug * 64 + tid] =
                red[0][tid] + red[1][tid] + red[2][tid] + red[3][tid] + b1[ug * 64 + tid];
    } else {
        ctx[(blockIdx.x - 384) * 256 + tid] = 0.f;   // 64 blocks x 256 = 16384
    }
}

// ---- kernel 1: fused GEMM + tanh + dot(W2) -> e2 (round-0 body, verbatim —
// best measured variant: 89-94 µs, VGPR 60, 0 bank conflicts, no spill).
// 512 thr = 8 waves; block tile 64 rows x 512 cols (full U) x K=512.
// Wave tile 64x64 (acc 4x4 = 64 VGPR) -> launch_bounds(512,4) = 4 waves/SIMD.
// A staged once to LDS in A-frag order; barrier-free K-loop; no atomics.
__global__ __launch_bounds__(512, 4) void kgemm(
        const float* __restrict__ A, const ushort* __restrict__ Wp,
        const float* __restrict__ dec, const float* __restrict__ W2,
        float* __restrict__ e2) {
    __shared__ __align__(16) ushort As[32768];   // 64 KB
    __shared__ float red[8][64];                 // 2 KB
    const int tid = threadIdx.x;
    const int rowbase = blockIdx.x * 64;
    const int bIdx = blockIdx.x >> 5;            // 32 blocks per batch

    // stage A tile: 64 rows x 512 k, fp32 -> bf16, fragment-chunk order
    #pragma unroll
    for (int p = 0; p < 8; ++p) {
        int s = tid + 512 * p;                   // 0..4095 lane-slots
        int chunk = s >> 6, l = s & 63;
        int i = chunk >> 4, kc = chunk & 15;
        int m = l & 15, gg = l >> 4;
        const float* gp = A + (size_t)(rowbase + i * 16 + m) * 512 + kc * 32 + gg * 8;
        float4 f0 = *(const float4*)gp;
        float4 f1 = *(const float4*)(gp + 4);
        uint4 u;
        u.x = packbf2(f0.x, f0.y); u.y = packbf2(f0.z, f0.w);
        u.z = packbf2(f1.x, f1.y); u.w = packbf2(f1.z, f1.w);
        *(uint4*)&As[chunk * 512 + l * 8] = u;
    }
    __syncthreads();

    const int lane = tid & 63, wave = tid >> 6;
    const int c = lane & 15, g = lane >> 4;

    floatx4 acc[4][4];
    #pragma unroll
    for (int i = 0; i < 4; i++)
        #pragma unroll
        for (int j = 0; j < 4; j++) acc[i][j] = (floatx4){0.f, 0.f, 0.f, 0.f};

    const int ng0 = wave * 4;                    // wave covers cols wave*64..+63
    #pragma unroll 2
    for (int kc = 0; kc < 16; ++kc) {
        short8 bfr[4];
        #pragma unroll
        for (int j = 0; j < 4; ++j)
            bfr[j] = *(const short8*)&Wp[(size_t)(kc * 32 + ng0 + j) * 512 + lane * 8];
        short8 afr[4];
        #pragma unroll
        for (int i = 0; i < 4; ++i)
            afr[i] = *(const short8*)&As[(i * 16 + kc) * 512 + lane * 8];
        #pragma unroll
        for (int j = 0; j < 4; ++j)
            #pragma unroll
            for (int i = 0; i < 4; ++i)
                acc[i][j] = __builtin_amdgcn_mfma_f32_16x16x32_bf16(afr[i], bfr[j], acc[i][j], 0, 0, 0);
    }

    // epilogue: z += dec; p = sum_u tanh(z)*W2[u]; reduce 16 lanes + 8 waves
    float w2v[4], dv[4];
    #pragma unroll
    for (int j = 0; j < 4; j++) {
        int n = wave * 64 + j * 16 + c;
        w2v[j] = W2[n];
        dv[j]  = dec[bIdx * 512 + n];
    }
    #pragma unroll
    for (int i = 0; i < 4; i++) {
        #pragma unroll
        for (int r = 0; r < 4; r++) {
            float p = 0.f;
            #pragma unroll
            for (int j = 0; j < 4; j++)
                p += tanh_fast(acc[i][j][r] + dv[j]) * w2v[j];
            p += __shfl_xor(p, 1, 16);
            p += __shfl_xor(p, 2, 16);
            p += __shfl_xor(p, 4, 16);
            p += __shfl_xor(p, 8, 16);
            if (c == 0) red[wave][i * 16 + g * 4 + r] = p;
        }
    }
    __syncthreads();
    if (tid < 64) {
        float s = 0.f;
        #pragma unroll
        for (int w = 0; w < 8; ++w) s += red[w][tid];
        e2[rowbase + tid] = s;
    }
}

// ---- kernel 2: fused softmax + partial context -> atomicAdd into ctx (proven,
// rounds 5/7/10). Block (b,ch): recompute row softmax stats from e2 (fixed
// reduction order => identical across blocks of same b), write own 64-wide
// attn slice, then ctx[b][:] += sum_{t in chunk} attn*h_enc.
__global__ __launch_bounds__(512) void kctx2(const float* __restrict__ A,
        const float* __restrict__ e2, const float* __restrict__ b2,
        float* __restrict__ attn, float* __restrict__ ctx) {
    __shared__ float at[64];
    __shared__ float4 red[3][128];
    __shared__ float smax[8], ssum[8];
    int b = blockIdx.x, ch = blockIdx.y, tid = threadIdx.x;
    int lane = tid & 63, wave = tid >> 6;
    float b2v = b2[0];
    const float* erow = e2 + b * 2048;

    float f[4];
    float mx = 0.f;                                   // relu values >= 0
    #pragma unroll
    for (int i = 0; i < 4; i++) {
        f[i] = fmaxf(erow[i * 512 + tid] + b2v, 0.f);
        mx = fmaxf(mx, f[i]);
    }
    #pragma unroll
    for (int off = 1; off < 64; off <<= 1) mx = fmaxf(mx, __shfl_xor(mx, off));
    if (lane == 0) smax[wave] = mx;
    __syncthreads();
    #pragma unroll
    for (int w = 0; w < 8; ++w) mx = fmaxf(mx, smax[w]);
    float s = 0.f;
    #pragma unroll
    for (int i = 0; i < 4; i++) s += __expf(f[i] - mx);
    #pragma unroll
    for (int off = 1; off < 64; off <<= 1) s += __shfl_xor(s, off);
    if (lane == 0) ssum[wave] = s;
    __syncthreads();
    s = 0.f;
    #pragma unroll
    for (int w = 0; w < 8; ++w) s += ssum[w];
    float inv = 1.f / s;

    if (tid < 64) {
        float z = fmaxf(erow[ch * 64 + tid] + b2v, 0.f);
        float a = __expf(z - mx) * inv;
        at[tid] = a;
        attn[b * 2048 + ch * 64 + tid] = a;
    }
    __syncthreads();

    int dt = tid & 127, th = tid >> 7;               // th in 0..3, 16 t each
    const float* base = A + ((size_t)b * 2048 + ch * 64 + th * 16) * 512 + dt * 4;
    const float* aw = at + th * 16;
    float4 acc = (float4){0.f, 0.f, 0.f, 0.f};
    #pragma unroll
    for (int tt = 0; tt < 16; ++tt) {
        float a = aw[tt];
        float4 h = *(const float4*)(base + (size_t)tt * 512);
        acc.x += a * h.x; acc.y += a * h.y; acc.z += a * h.z; acc.w += a * h.w;
    }
    if (th) red[th - 1][dt] = acc;
    __syncthreads();
    if (th == 0) {
        float4 o0 = red[0][dt], o1 = red[1][dt], o2 = red[2][dt];
        float* cp = ctx + (size_t)b * 512 + dt * 4;
        atomicAdd(cp + 0, acc.x + o0.x + o1.x + o2.x);
        atomicAdd(cp + 1, acc.y + o0.y + o1.y + o2.y);
        atomicAdd(cp + 2, acc.z + o0.z + o1.z + o2.z);
        atomicAdd(cp + 3, acc.w + o0.w + o1.w + o2.w);
    }
}

extern "C" void kernel_launch(void* const* d_in, const int* in_sizes, int n_in,
                              void* d_out, int out_size, void* d_ws, size_t ws_size,
                              hipStream_t stream) {
    const float* h_enc = (const float*)d_in[0];
    const float* h_dec = (const float*)d_in[1];
    const float* W1    = (const float*)d_in[2];
    const float* b1    = (const float*)d_in[3];
    const float* W2    = (const float*)d_in[4];
    const float* b2    = (const float*)d_in[5];
    float* out  = (float*)d_out;
    float* ctx  = out;              // 32*512
    float* attn = out + 32 * 512;   // 32*2048

    char* ws = (char*)d_ws;
    ushort* Wp = (ushort*)ws;                          // 512 KB @ 0
    float* dec  = (float*)(ws + (512 << 10));          // 64 KB  @ 512K
    float* e2   = (float*)(ws + (576 << 10));          // 256 KB @ 576K

    kprep<<<448, 256, 0, stream>>>(W1, h_dec, b1, Wp, dec, ctx);
    kgemm<<<1024, 512, 0, stream>>>(h_enc, Wp, dec, W2, e2);
    dim3 g3(32, 32);
    kctx2<<<g3, 512, 0, stream>>>(h_enc, e2, b2, attn, ctx);
}